// Round 6
// baseline (2077.476 us; speedup 1.0000x reference)
//
#include <hip/hip_runtime.h>
#include <hip/hip_bf16.h>

typedef unsigned short u16;
typedef unsigned int u32;

static __device__ __forceinline__ float us2f(u16 u) {
    return __uint_as_float(((u32)u) << 16);
}
static __device__ __forceinline__ u16 f2bu(float f) {  // RNE
    u32 u = __float_as_uint(f);
    return (u16)((u + 0x7fffu + ((u >> 16) & 1u)) >> 16);
}

typedef __attribute__((ext_vector_type(8))) __bf16 bf16x8;
typedef __attribute__((ext_vector_type(4))) float f32x4;

__global__ void fill_sentinel(float* out, int n, float val) {
    int g = blockIdx.x * 256 + threadIdx.x;
    if (g < n) out[g] = val;
}

// ============================================================
// Kernel 1: conv1 9x9 s1 + bias + relu -> h NHWC bf16 [B][20][20][256]
// grid B*4 (4 groups of 5 output rows), block 256 (=channel)
// ============================================================
__global__ __launch_bounds__(256) void conv1_kernel(const float* __restrict__ x,
    const float* __restrict__ w, const float* __restrict__ bias, u16* __restrict__ h)
{
    __shared__ float xs[784];
    __shared__ u16 wl[81 * 256];   // [tap][channel] bf16
    const int b = blockIdx.x >> 2, g = blockIdx.x & 3;
    const int c = threadIdx.x;
    for (int idx = c; idx < 784; idx += 256) xs[idx] = x[b * 784 + idx];
    #pragma unroll 1
    for (int j = 0; j < 81; ++j) wl[j * 256 + c] = f2bu(w[c * 81 + j]);
    __syncthreads();
    const float bv = bias[c];
    #pragma unroll 1
    for (int iy = g * 5; iy < g * 5 + 5; ++iy) {
        float acc[20];
        #pragma unroll
        for (int i = 0; i < 20; ++i) acc[i] = bv;
        #pragma unroll 1
        for (int dy = 0; dy < 9; ++dy) {
            float xr[28];
            #pragma unroll
            for (int i = 0; i < 28; ++i) xr[i] = xs[(iy + dy) * 28 + i];
            #pragma unroll
            for (int dx = 0; dx < 9; ++dx) {
                const float wv = us2f(wl[(dy * 9 + dx) * 256 + c]);
                #pragma unroll
                for (int ix = 0; ix < 20; ++ix) acc[ix] += xr[ix + dx] * wv;
            }
        }
        u16* hp = h + ((b * 20 + iy) * 20) * 256 + c;
        #pragma unroll
        for (int ix = 0; ix < 20; ++ix) hp[ix * 256] = f2bu(fmaxf(acc[ix], 0.f));
    }
}

// ============================================================
// Kernel 2: transpose prim_w f32 [n][c][kyx] -> wT2 bf16 [n][kyx][c]
// ============================================================
__global__ __launch_bounds__(256) void transpose_primw(const float* __restrict__ w,
                                                       u16* __restrict__ wt)
{
    const int o = blockIdx.x * 256 + threadIdx.x;   // 5,308,416 total
    const int c = o & 255; const int r = o >> 8;
    const int kyx = r % 81; const int n = r / 81;
    wt[(n * 81 + kyx) * 256 + c] = f2bu(w[(size_t)(n * 256 + c) * 81 + kyx]);
}

// ============================================================
// Kernel 3: primary-caps implicit GEMM (MFMA bf16 16x16x32), K=20736,
// fused /32 + prim_b + squash(8 atoms) -> x3 f32 [B][1152][8]
// grid 144, block 256 (4 waves 2x2), 128x128 tile, BK=32.
// ============================================================
__global__ __launch_bounds__(256) void prim_gemm_fused(const u16* __restrict__ h,
    const u16* __restrict__ wT, const float* __restrict__ prim_b, float* __restrict__ x3)
{
    __shared__ u16 As[128 * 32];
    __shared__ u16 Bs[128 * 32];
    const int tid = threadIdx.x;
    const int mt = blockIdx.x % 72, nt = blockIdx.x / 72;
    const int mBase = mt * 128, nBase = nt * 128;
    const int tq = tid & 3, tr = tid >> 2;
    int m0 = mBase + tr;
    int b0 = m0 / 36, r0 = m0 % 36;
    int aBase0 = ((b0 * 20 + 2 * (r0 / 6)) * 20 + 2 * (r0 % 6)) * 256 + tq * 8;
    int m1 = m0 + 64;
    int b1 = m1 / 36, r1 = m1 % 36;
    int aBase1 = ((b1 * 20 + 2 * (r1 / 6)) * 20 + 2 * (r1 % 6)) * 256 + tq * 8;
    const int bBase0 = (nBase + tr) * 20736 + tq * 8;
    const int bBase1 = (nBase + tr + 64) * 20736 + tq * 8;
    int kglob = 0, ky = 0, kx = 0, c0 = 0;

    f32x4 acc[4][4];
    #pragma unroll
    for (int i = 0; i < 4; ++i)
        #pragma unroll
        for (int j = 0; j < 4; ++j) acc[i][j] = (f32x4){0.f, 0.f, 0.f, 0.f};

    const int lane = tid & 63;
    const int wvi = tid >> 6; const int wm = wvi >> 1, wn = wvi & 1;
    const int lcol = lane & 15, lquad = lane >> 4;
    const u16* Arow = As + (wm * 64 + lcol) * 32 + lquad * 8;
    const u16* Brow = Bs + (wn * 64 + lcol) * 32 + lquad * 8;

    #pragma unroll 1
    for (int kt = 0; kt < 648; ++kt) {
        const int koffA = (ky * 20 + kx) * 256 + c0;
        uint4 ra0 = *reinterpret_cast<const uint4*>(h + aBase0 + koffA);
        uint4 ra1 = *reinterpret_cast<const uint4*>(h + aBase1 + koffA);
        uint4 rb0 = *reinterpret_cast<const uint4*>(wT + bBase0 + kglob);
        uint4 rb1 = *reinterpret_cast<const uint4*>(wT + bBase1 + kglob);
        __syncthreads();
        *reinterpret_cast<uint4*>(As + tid * 8)        = ra0;
        *reinterpret_cast<uint4*>(As + 2048 + tid * 8) = ra1;
        *reinterpret_cast<uint4*>(Bs + tid * 8)        = rb0;
        *reinterpret_cast<uint4*>(Bs + 2048 + tid * 8) = rb1;
        __syncthreads();
        bf16x8 af[4], bfr[4];
        #pragma unroll
        for (int i = 0; i < 4; ++i)
            af[i] = *reinterpret_cast<const bf16x8*>(Arow + i * 512);
        #pragma unroll
        for (int j = 0; j < 4; ++j)
            bfr[j] = *reinterpret_cast<const bf16x8*>(Brow + j * 512);
        #pragma unroll
        for (int i = 0; i < 4; ++i)
            #pragma unroll
            for (int j = 0; j < 4; ++j)
                acc[i][j] = __builtin_amdgcn_mfma_f32_16x16x32_bf16(af[i], bfr[j], acc[i][j], 0, 0, 0);
        kglob += 32; c0 += 32;
        if (c0 == 256) { c0 = 0; if (++kx == 9) { kx = 0; ++ky; } }
    }
    // epilogue: C/D layout col(n)=lane&15, row(m)=quad*4+reg
    #pragma unroll
    for (int i = 0; i < 4; ++i) {
        #pragma unroll
        for (int j = 0; j < 4; ++j) {
            const int n = nBase + wn * 64 + j * 16 + lcol;
            const float pb = prim_b[n];
            #pragma unroll
            for (int r = 0; r < 4; ++r) {
                const int m = mBase + wm * 64 + i * 16 + lquad * 4 + r;
                float pre = acc[i][j][r] * (1.f / 32.f) + pb;
                float sq = pre * pre;
                sq += __shfl_xor(sq, 1); sq += __shfl_xor(sq, 2); sq += __shfl_xor(sq, 4);
                float scale = (sq / (1.f + sq)) * rsqrtf(sq + 1e-9f);
                const int b = m / 36, p = m % 36;
                x3[((size_t)(b * 1152 + (n >> 3) * 36 + p)) * 8 + (n & 7)] = pre * scale;
            }
        }
    }
}

// ============================================================
// Kernel 4: routing act (recomputes votes from x3·dw; all f32)
// grid B=256, block 256; threads 0..159 own (o,t)
// ============================================================
__global__ __launch_bounds__(256) void routing_act2(const float* __restrict__ x3,
    const float* __restrict__ dw, const float* __restrict__ logits,
    const float* __restrict__ digit_b, float* __restrict__ act,
    float* __restrict__ dout, int uniform)
{
    __shared__ float x3s[1152 * 8];
    __shared__ float rs[128 * 10];
    const int b = blockIdx.x;
    const int tid = threadIdx.x;
    for (int idx = tid; idx < 1152 * 8; idx += 256)
        x3s[idx] = x3[(size_t)b * 9216 + idx];
    const int o = tid >> 4, t = tid & 15;
    float pre = 0.f;
    #pragma unroll 1
    for (int c = 0; c < 9; ++c) {
        __syncthreads();
        if (tid < 128) {
            const int i = c * 128 + tid;
            if (uniform) {
                #pragma unroll
                for (int k = 0; k < 10; ++k) rs[tid * 10 + k] = 0.1f;
            } else {
                const float* lg = &logits[((size_t)b * 1152 + i) * 10];
                float l[10]; float mx = -1e30f;
                #pragma unroll
                for (int k = 0; k < 10; ++k) { l[k] = lg[k]; mx = fmaxf(mx, l[k]); }
                float s = 0.f;
                #pragma unroll
                for (int k = 0; k < 10; ++k) { l[k] = __expf(l[k] - mx); s += l[k]; }
                const float inv = 1.f / s;
                #pragma unroll
                for (int k = 0; k < 10; ++k) rs[tid * 10 + k] = l[k] * inv;
            }
        }
        __syncthreads();
        if (tid < 160) {
            #pragma unroll 2
            for (int il = 0; il < 128; ++il) {
                const int i = c * 128 + il;
                float v = 0.f;
                #pragma unroll
                for (int a = 0; a < 8; ++a)
                    v += x3s[i * 8 + a] * dw[(((size_t)i * 8 + a) * 10 + o) * 16 + t];
                pre += rs[il * 10 + o] * v;
            }
        }
    }
    if (tid < 160) {
        pre += digit_b[o * 16 + t];
        float sq = pre * pre;
        sq += __shfl_xor(sq, 1); sq += __shfl_xor(sq, 2);
        sq += __shfl_xor(sq, 4); sq += __shfl_xor(sq, 8);
        float scale = (sq / (1.f + sq)) * rsqrtf(sq + 1e-9f);
        float aout = pre * scale;
        act[(size_t)b * 160 + tid] = aout;
        if (dout) dout[(size_t)b * 160 + tid] = aout;
    }
}

// ============================================================
// Kernel 5: logits[b,i,o] (+)= sum_a x3[b,i,a]*(sum_t dw[i,a,o,t]*act[b,o,t])
// grid 2304 (b, i-chunk of 128), block 256 (2 threads/i, 5 o's each)
// ============================================================
__global__ __launch_bounds__(256) void routing_upd2(const float* __restrict__ x3,
    const float* __restrict__ dw, const float* __restrict__ act,
    float* __restrict__ logits, int first)
{
    __shared__ float acts[160];
    __shared__ float x3c[128 * 8];
    const int b = blockIdx.x / 9, c = blockIdx.x % 9;
    const int tid = threadIdx.x;
    if (tid < 160) acts[tid] = act[(size_t)b * 160 + tid];
    for (int q = tid; q < 1024; q += 256)
        x3c[q] = x3[(size_t)b * 9216 + c * 1024 + q];
    __syncthreads();
    const int il = tid >> 1, half = tid & 1;
    const int i = c * 128 + il;
    float lg[5];
    #pragma unroll
    for (int oo = 0; oo < 5; ++oo) {
        const int o = half * 5 + oo;
        float s = 0.f;
        #pragma unroll
        for (int a = 0; a < 8; ++a) {
            const float* dp = &dw[(((size_t)i * 8 + a) * 10 + o) * 16];
            float inner = 0.f;
            #pragma unroll
            for (int t = 0; t < 16; ++t) inner += dp[t] * acts[o * 16 + t];
            s += x3c[il * 8 + a] * inner;
        }
        lg[oo] = s;
    }
    float* lp = &logits[((size_t)b * 1152 + i) * 10 + half * 5];
    if (first) {
        #pragma unroll
        for (int oo = 0; oo < 5; ++oo) lp[oo] = lg[oo];
    } else {
        #pragma unroll
        for (int oo = 0; oo < 5; ++oo) lp[oo] += lg[oo];
    }
}

// ============================================================
// Kernel 6: masked[b][j] = act[b][j] * y[b][j/16]
// ============================================================
__global__ __launch_bounds__(256) void masked_kernel(const float* __restrict__ act,
    const float* __restrict__ y, float* __restrict__ masked)
{
    const int gid = blockIdx.x * 256 + threadIdx.x;  // 40960
    const int b = gid / 160, j = gid % 160;
    masked[gid] = act[gid] * y[b * 10 + (j >> 4)];
}

// ============================================================
// Kernel 7: dense layer; mode 0=relu, 1=sigmoid; all f32 out
// grid (B/4, ceil(N/256)), block 256
// ============================================================
__global__ __launch_bounds__(256) void mlp_layer(const float* __restrict__ in,
    const float* __restrict__ w, const float* __restrict__ bias,
    float* __restrict__ outp, int K, int N, int mode)
{
    __shared__ float ins[4 * 1024];
    const int b0 = blockIdx.x * 4;
    const int n = blockIdx.y * 256 + threadIdx.x;
    for (int idx = threadIdx.x; idx < 4 * K; idx += 256)
        ins[idx] = in[(size_t)b0 * K + idx];
    __syncthreads();
    if (n < N) {
        float a0 = 0.f, a1 = 0.f, a2 = 0.f, a3 = 0.f;
        for (int k = 0; k < K; ++k) {
            const float wvv = w[(size_t)k * N + n];
            a0 += ins[k] * wvv;
            a1 += ins[K + k] * wvv;
            a2 += ins[2 * K + k] * wvv;
            a3 += ins[3 * K + k] * wvv;
        }
        const float bv = bias[n];
        float v[4] = {a0 + bv, a1 + bv, a2 + bv, a3 + bv};
        #pragma unroll
        for (int j = 0; j < 4; ++j) {
            float xv = v[j];
            xv = (mode == 0) ? fmaxf(xv, 0.f) : 1.f / (1.f + __expf(-xv));
            outp[(size_t)(b0 + j) * N + n] = xv;
        }
    }
}

// ============================================================
extern "C" void kernel_launch(void* const* d_in, const int* in_sizes, int n_in,
                              void* d_out, int out_size, void* d_ws, size_t ws_size,
                              hipStream_t stream) {
    const float* x   = (const float*)d_in[0];
    const float* y   = (const float*)d_in[1];
    const float* c1w = (const float*)d_in[2];
    const float* c1b = (const float*)d_in[3];
    const float* pw  = (const float*)d_in[4];
    const float* pb  = (const float*)d_in[5];
    const float* dw  = (const float*)d_in[6];
    const float* db  = (const float*)d_in[7];
    const float* w1  = (const float*)d_in[8];
    const float* b1  = (const float*)d_in[9];
    const float* w2  = (const float*)d_in[10];
    const float* b2  = (const float*)d_in[11];
    const float* w3  = (const float*)d_in[12];
    const float* b3  = (const float*)d_in[13];
    float* out = (float*)d_out;                        // f32 outputs (digit | recon)
    char* ws = (char*)d_ws;

    // host-side guards (cost nothing when healthy)
    static const int exp_sizes[14] = {200704, 2560, 20736, 256, 5308416, 256,
                                      1474560, 160, 81920, 512, 524288, 1024,
                                      802816, 784};
    int bad = (n_in == 14) ? -1 : -2;
    if (bad == -1)
        for (int i = 0; i < 14; ++i) if (in_sizes[i] != exp_sizes[i]) { bad = i; break; }
    if (bad != -1) {
        fill_sentinel<<<(out_size + 255) / 256, 256, 0, stream>>>(out, out_size,
            7168.f + 16.f * (float)(bad + 1));
        return;
    }
    const size_t NEEDED = 72482816ULL;
    if (ws_size < NEEDED) {
        fill_sentinel<<<(out_size + 255) / 256, 256, 0, stream>>>(out, out_size, 111.0f);
        return;
    }

    u16*   h      = (u16*)(ws);                    // [0, 52,428,800)
    u16*   wT2    = (u16*)(ws + 52428800);         // [52,428,800, 63,045,632)
    float* x3     = (float*)(ws + 63045632);       // [63,045,632, 72,482,816)
    float* logits = (float*)(ws);                  // overlays dead h
    float* act    = (float*)(ws + 11796480);
    float* masked = (float*)(ws + 11960320);
    float* r1     = (float*)(ws + 12124160);
    float* r2     = (float*)(ws + 12648448);

    conv1_kernel<<<1024, 256, 0, stream>>>(x, c1w, c1b, h);
    transpose_primw<<<20736, 256, 0, stream>>>(pw, wT2);
    prim_gemm_fused<<<144, 256, 0, stream>>>(h, wT2, pb, x3);
    // routing: act1(uniform) -> logits=V·a1 -> act2 -> logits+=V·a2 -> act3(out)
    routing_act2<<<256, 256, 0, stream>>>(x3, dw, logits, db, act, (float*)nullptr, 1);
    routing_upd2<<<2304, 256, 0, stream>>>(x3, dw, act, logits, 1);
    routing_act2<<<256, 256, 0, stream>>>(x3, dw, logits, db, act, (float*)nullptr, 0);
    routing_upd2<<<2304, 256, 0, stream>>>(x3, dw, act, logits, 0);
    routing_act2<<<256, 256, 0, stream>>>(x3, dw, logits, db, act, out, 0);
    // reconstruction
    masked_kernel<<<160, 256, 0, stream>>>(act, y, masked);
    mlp_layer<<<dim3(64, 2), 256, 0, stream>>>(masked, w1, b1, r1, 160, 512, 0);
    mlp_layer<<<dim3(64, 4), 256, 0, stream>>>(r1, w2, b2, r2, 512, 1024, 0);
    mlp_layer<<<dim3(64, 4), 256, 0, stream>>>(r2, w3, b3, out + 40960, 1024, 784, 1);
}

// Round 7
// 932.709 us; speedup vs baseline: 2.2274x; 2.2274x over previous
//
#include <hip/hip_runtime.h>
#include <hip/hip_bf16.h>

typedef unsigned short u16;
typedef unsigned int u32;

static __device__ __forceinline__ float us2f(u16 u) {
    return __uint_as_float(((u32)u) << 16);
}
static __device__ __forceinline__ u16 f2bu(float f) {  // RNE
    u32 u = __float_as_uint(f);
    return (u16)((u + 0x7fffu + ((u >> 16) & 1u)) >> 16);
}

typedef __attribute__((ext_vector_type(8))) __bf16 bf16x8;
typedef __attribute__((ext_vector_type(4))) float f32x4;

__global__ void fill_sentinel(float* out, int n, float val) {
    int g = blockIdx.x * 256 + threadIdx.x;
    if (g < n) out[g] = val;
}

// ============================================================
// Kernel 1: conv1 9x9 s1 + bias + relu -> h NHWC bf16 [B][20][20][256]
// grid B*4, block 256 (=channel). Weight staging coalesced via LDS scatter.
// ============================================================
__global__ __launch_bounds__(256) void conv1_kernel(const float* __restrict__ x,
    const float* __restrict__ w, const float* __restrict__ bias, u16* __restrict__ h)
{
    __shared__ float xs[784];
    __shared__ u16 wl[81 * 256];   // [tap][channel] bf16
    const int b = blockIdx.x >> 2, g = blockIdx.x & 3;
    const int c = threadIdx.x;
    for (int idx = c; idx < 784; idx += 256) xs[idx] = x[b * 784 + idx];
    for (int idx = c; idx < 20736; idx += 256) {      // coalesced read, LDS scatter
        const int cc = idx / 81, jj = idx - cc * 81;
        wl[jj * 256 + cc] = f2bu(w[idx]);
    }
    __syncthreads();
    const float bv = bias[c];
    #pragma unroll 1
    for (int iy = g * 5; iy < g * 5 + 5; ++iy) {
        float acc[20];
        #pragma unroll
        for (int i = 0; i < 20; ++i) acc[i] = bv;
        #pragma unroll 1
        for (int dy = 0; dy < 9; ++dy) {
            float xr[28];
            #pragma unroll
            for (int i = 0; i < 28; ++i) xr[i] = xs[(iy + dy) * 28 + i];
            #pragma unroll
            for (int dx = 0; dx < 9; ++dx) {
                const float wv = us2f(wl[(dy * 9 + dx) * 256 + c]);
                #pragma unroll
                for (int ix = 0; ix < 20; ++ix) acc[ix] += xr[ix + dx] * wv;
            }
        }
        u16* hp = h + ((b * 20 + iy) * 20) * 256 + c;
        #pragma unroll
        for (int ix = 0; ix < 20; ++ix) hp[ix * 256] = f2bu(fmaxf(acc[ix], 0.f));
    }
}

// ============================================================
// Kernel 2: transpose prim_w f32 [n][c][kyx] -> wT2 bf16 [n][kyx][c]
// grid 256 (=n), block 256. LDS bounce: coalesced read AND write.
// ============================================================
__global__ __launch_bounds__(256) void transpose_primw(const float* __restrict__ w,
                                                       u16* __restrict__ wt)
{
    __shared__ u16 wl[20736];
    const int n = blockIdx.x, tid = threadIdx.x;
    const float* ws = w + (size_t)n * 20736;
    for (int idx = tid; idx < 20736; idx += 256) {
        const int cc = idx / 81, kk = idx - cc * 81;
        wl[kk * 256 + cc] = f2bu(ws[idx]);
    }
    __syncthreads();
    u16* wo = wt + (size_t)n * 20736;
    for (int q = tid; q < 20736; q += 256) wo[q] = wl[q];
}

// ============================================================
// Kernel 3: primary-caps implicit GEMM, MFMA bf16 16x16x32, split-K=8.
// grid (144, 8), block 256 (4 waves 2x2), 128x128 tile, BK=32, K=2592/split.
// LDS rows padded 32->40 u16 (kills 4-way read conflicts).
// Epilogue: f32 HW atomics into preactM[m][n] (zero-initialized).
// ============================================================
__global__ __launch_bounds__(256) void prim_gemm_split(const u16* __restrict__ h,
    const u16* __restrict__ wT, float* __restrict__ pm)
{
    __shared__ u16 As[128 * 40];
    __shared__ u16 Bs[128 * 40];
    const int tid = threadIdx.x;
    const int split = blockIdx.y;
    const int mt = blockIdx.x % 72, nt = blockIdx.x / 72;
    const int mBase = mt * 128, nBase = nt * 128;
    const int tq = tid & 3, tr = tid >> 2;
    int m0 = mBase + tr;
    int b0 = m0 / 36, r0 = m0 % 36;
    int aBase0 = ((b0 * 20 + 2 * (r0 / 6)) * 20 + 2 * (r0 % 6)) * 256 + tq * 8;
    int m1 = m0 + 64;
    int b1 = m1 / 36, r1 = m1 % 36;
    int aBase1 = ((b1 * 20 + 2 * (r1 / 6)) * 20 + 2 * (r1 % 6)) * 256 + tq * 8;
    const int bBase0 = (nBase + tr) * 20736 + tq * 8;
    const int bBase1 = (nBase + tr + 64) * 20736 + tq * 8;
    // split covers k in [split*2592, (split+1)*2592), k = ky*2304 + kx*256 + c
    int kglob = split * 2592;
    int ky = kglob / 2304; int krem = kglob - ky * 2304;
    int kx = krem >> 8; int c0 = krem & 255;

    f32x4 acc[4][4];
    #pragma unroll
    for (int i = 0; i < 4; ++i)
        #pragma unroll
        for (int j = 0; j < 4; ++j) acc[i][j] = (f32x4){0.f, 0.f, 0.f, 0.f};

    const int lane = tid & 63;
    const int wvi = tid >> 6; const int wm = wvi >> 1, wn = wvi & 1;
    const int lcol = lane & 15, lquad = lane >> 4;
    const u16* Arow = As + (wm * 64 + lcol) * 40 + lquad * 8;
    const u16* Brow = Bs + (wn * 64 + lcol) * 40 + lquad * 8;

    #pragma unroll 1
    for (int kt = 0; kt < 81; ++kt) {
        const int koffA = (ky * 20 + kx) * 256 + c0;
        uint4 ra0 = *reinterpret_cast<const uint4*>(h + aBase0 + koffA);
        uint4 ra1 = *reinterpret_cast<const uint4*>(h + aBase1 + koffA);
        uint4 rb0 = *reinterpret_cast<const uint4*>(wT + bBase0 + kglob);
        uint4 rb1 = *reinterpret_cast<const uint4*>(wT + bBase1 + kglob);
        __syncthreads();
        *reinterpret_cast<uint4*>(As + tr * 40 + tq * 8)        = ra0;
        *reinterpret_cast<uint4*>(As + (tr + 64) * 40 + tq * 8) = ra1;
        *reinterpret_cast<uint4*>(Bs + tr * 40 + tq * 8)        = rb0;
        *reinterpret_cast<uint4*>(Bs + (tr + 64) * 40 + tq * 8) = rb1;
        __syncthreads();
        bf16x8 af[4], bfr[4];
        #pragma unroll
        for (int i = 0; i < 4; ++i)
            af[i] = *reinterpret_cast<const bf16x8*>(Arow + i * 640);
        #pragma unroll
        for (int j = 0; j < 4; ++j)
            bfr[j] = *reinterpret_cast<const bf16x8*>(Brow + j * 640);
        #pragma unroll
        for (int i = 0; i < 4; ++i)
            #pragma unroll
            for (int j = 0; j < 4; ++j)
                acc[i][j] = __builtin_amdgcn_mfma_f32_16x16x32_bf16(af[i], bfr[j], acc[i][j], 0, 0, 0);
        kglob += 32; c0 += 32;
        if (c0 == 256) { c0 = 0; if (++kx == 9) { kx = 0; ++ky; } }
    }
    // epilogue: atomic add raw partials into pm[m*256+n]
    #pragma unroll
    for (int i = 0; i < 4; ++i) {
        const int mrow = mBase + wm * 64 + i * 16 + lquad * 4;
        #pragma unroll
        for (int j = 0; j < 4; ++j) {
            const int ncol = nBase + wn * 64 + j * 16 + lcol;
            #pragma unroll
            for (int r = 0; r < 4; ++r)
                unsafeAtomicAdd(&pm[(size_t)(mrow + r) * 256 + ncol], acc[i][j][r]);
        }
    }
}

// ============================================================
// Kernel 4: in-place /32 + prim_b + squash over 8-atom groups.
// pm is [m=9216][n=256] with n = cap*8+atom; squash is row-local -> no race.
// ============================================================
__global__ __launch_bounds__(256) void squash_kernel(float* __restrict__ pm,
    const float* __restrict__ pb)
{
    const int m = blockIdx.x, t = threadIdx.x;
    float pre = pm[(size_t)m * 256 + t] * (1.f / 32.f) + pb[t];
    float sq = pre * pre;
    sq += __shfl_xor(sq, 1); sq += __shfl_xor(sq, 2); sq += __shfl_xor(sq, 4);
    float scale = (sq / (1.f + sq)) * rsqrtf(sq + 1e-9f);
    pm[(size_t)m * 256 + t] = pre * scale;
}

// ============================================================
// Kernel 5: routing preact partial. grid (9 i-chunks, 32 b-groups), block 256.
// Each block: 8 b's x 128 i; dw slice read ONCE serves 8 b's.
// preactD[b][160] accumulated via f32 atomics (zeroed before call).
// x3m layout: [b][p(36)][cap*8+atom]; i = cap*36+p.
// ============================================================
__global__ __launch_bounds__(256) void routing_act_part(const float* __restrict__ x3m,
    const float* __restrict__ dw, const float* __restrict__ logits,
    float* __restrict__ preactD, int uniform)
{
    __shared__ float x3s[8192];    // [b][il][a] 32 KB
    __shared__ float rs[10240];    // [b][il][o] 40 KB
    const int c = blockIdx.x, bg = blockIdx.y;
    const int tid = threadIdx.x;
    for (int q = tid; q < 8192; q += 256) {
        const int b_l = q >> 10, rest = q & 1023, il = rest >> 3, a = rest & 7;
        const int i = c * 128 + il, cap = i / 36, p = i - cap * 36;
        x3s[q] = x3m[((size_t)(bg * 8 + b_l) * 36 + p) * 256 + cap * 8 + a];
    }
    if (!uniform && tid < 128) {
        const int i = c * 128 + tid;
        for (int b_l = 0; b_l < 8; ++b_l) {
            const float* lg = &logits[((size_t)(bg * 8 + b_l) * 1152 + i) * 10];
            float l[10]; float mx = -1e30f;
            #pragma unroll
            for (int k = 0; k < 10; ++k) { l[k] = lg[k]; mx = fmaxf(mx, l[k]); }
            float s = 0.f;
            #pragma unroll
            for (int k = 0; k < 10; ++k) { l[k] = __expf(l[k] - mx); s += l[k]; }
            const float inv = 1.f / s;
            #pragma unroll
            for (int k = 0; k < 10; ++k) rs[(b_l * 128 + tid) * 10 + k] = l[k] * inv;
        }
    }
    __syncthreads();
    if (tid < 160) {
        const int o = tid >> 4, t = tid & 15;
        float preg[8];
        #pragma unroll
        for (int b_l = 0; b_l < 8; ++b_l) preg[b_l] = 0.f;
        #pragma unroll 1
        for (int il = 0; il < 128; ++il) {
            const int i = c * 128 + il;
            float dv[8];
            #pragma unroll
            for (int a = 0; a < 8; ++a)
                dv[a] = dw[(((size_t)i * 8 + a) * 10 + o) * 16 + t];
            #pragma unroll
            for (int b_l = 0; b_l < 8; ++b_l) {
                const float* xp = &x3s[(b_l * 128 + il) * 8];
                float v = 0.f;
                #pragma unroll
                for (int a = 0; a < 8; ++a) v += xp[a] * dv[a];
                const float r = uniform ? 0.1f : rs[(b_l * 128 + il) * 10 + o];
                preg[b_l] += r * v;
            }
        }
        #pragma unroll
        for (int b_l = 0; b_l < 8; ++b_l)
            unsafeAtomicAdd(&preactD[(size_t)(bg * 8 + b_l) * 160 + tid], preg[b_l]);
    }
}

// ============================================================
// Kernel 6: routing squash: preactD + digit_b -> squash -> act (+digit out)
// grid 256 (b), block 192 (160 active)
// ============================================================
__global__ __launch_bounds__(192) void routing_squash(const float* __restrict__ preactD,
    const float* __restrict__ db, float* __restrict__ act, float* __restrict__ dout)
{
    const int b = blockIdx.x, tid = threadIdx.x;
    if (tid < 160) {
        float pre = preactD[(size_t)b * 160 + tid] + db[tid];
        float sq = pre * pre;
        sq += __shfl_xor(sq, 1); sq += __shfl_xor(sq, 2);
        sq += __shfl_xor(sq, 4); sq += __shfl_xor(sq, 8);
        float scale = (sq / (1.f + sq)) * rsqrtf(sq + 1e-9f);
        float a = pre * scale;
        act[(size_t)b * 160 + tid] = a;
        if (dout) dout[(size_t)b * 160 + tid] = a;
    }
}

// ============================================================
// Kernel 7: logits update. grid (9, 32), block 256 = 128 i x 2 o-halves; 8 b's inside.
// logits[b,i,o] (+)= sum_a x3[b,i,a]*(sum_t dw[i,a,o,t]*act[b,o,t])
// ============================================================
__global__ __launch_bounds__(256) void routing_upd_part(const float* __restrict__ x3m,
    const float* __restrict__ dw, const float* __restrict__ act,
    float* __restrict__ logits, int first)
{
    __shared__ float x3s[8192];
    __shared__ float acts[1280];
    const int c = blockIdx.x, bg = blockIdx.y;
    const int tid = threadIdx.x;
    for (int q = tid; q < 8192; q += 256) {
        const int b_l = q >> 10, rest = q & 1023, il = rest >> 3, a = rest & 7;
        const int i = c * 128 + il, cap = i / 36, p = i - cap * 36;
        x3s[q] = x3m[((size_t)(bg * 8 + b_l) * 36 + p) * 256 + cap * 8 + a];
    }
    for (int q = tid; q < 1280; q += 256)
        acts[q] = act[(size_t)(bg * 8 + q / 160) * 160 + (q % 160)];
    __syncthreads();
    const int il = tid >> 1, half = tid & 1;
    const int i = c * 128 + il;
    #pragma unroll 1
    for (int oo = 0; oo < 5; ++oo) {
        const int o = half * 5 + oo;
        float s[8];
        #pragma unroll
        for (int b_l = 0; b_l < 8; ++b_l) s[b_l] = 0.f;
        #pragma unroll
        for (int a = 0; a < 8; ++a) {
            const float* dp = &dw[(((size_t)i * 8 + a) * 10 + o) * 16];
            float d[16];
            #pragma unroll
            for (int t = 0; t < 16; ++t) d[t] = dp[t];
            #pragma unroll
            for (int b_l = 0; b_l < 8; ++b_l) {
                const float* ap = &acts[b_l * 160 + o * 16];
                float inner = 0.f;
                #pragma unroll
                for (int t = 0; t < 16; ++t) inner += d[t] * ap[t];
                s[b_l] += x3s[(b_l * 128 + il) * 8 + a] * inner;
            }
        }
        #pragma unroll
        for (int b_l = 0; b_l < 8; ++b_l) {
            float* lp = &logits[((size_t)(bg * 8 + b_l) * 1152 + i) * 10 + o];
            if (first) *lp = s[b_l]; else *lp += s[b_l];
        }
    }
}

// ============================================================
// Kernel 8: masked[b][j] = act[b][j] * y[b][j/16]
// ============================================================
__global__ __launch_bounds__(256) void masked_kernel(const float* __restrict__ act,
    const float* __restrict__ y, float* __restrict__ masked)
{
    const int gid = blockIdx.x * 256 + threadIdx.x;  // 40960
    const int b = gid / 160, j = gid % 160;
    masked[gid] = act[gid] * y[b * 10 + (j >> 4)];
}

// ============================================================
// Kernel 9: dense layer; 2 batch rows/block; mode 0=relu, 1=sigmoid
// grid (B/2, ceil(N/256)), block 256
// ============================================================
__global__ __launch_bounds__(256) void mlp_layer(const float* __restrict__ in,
    const float* __restrict__ w, const float* __restrict__ bias,
    float* __restrict__ outp, int K, int N, int mode)
{
    __shared__ float ins[2 * 1024];
    const int b0 = blockIdx.x * 2;
    const int n = blockIdx.y * 256 + threadIdx.x;
    for (int idx = threadIdx.x; idx < 2 * K; idx += 256)
        ins[idx] = in[(size_t)b0 * K + idx];
    __syncthreads();
    if (n < N) {
        float a0 = 0.f, a1 = 0.f;
        for (int k = 0; k < K; ++k) {
            const float wvv = w[(size_t)k * N + n];
            a0 += ins[k] * wvv;
            a1 += ins[K + k] * wvv;
        }
        const float bv = bias[n];
        float v[2] = {a0 + bv, a1 + bv};
        #pragma unroll
        for (int j = 0; j < 2; ++j) {
            float xv = v[j];
            xv = (mode == 0) ? fmaxf(xv, 0.f) : 1.f / (1.f + __expf(-xv));
            outp[(size_t)(b0 + j) * N + n] = xv;
        }
    }
}

// ============================================================
extern "C" void kernel_launch(void* const* d_in, const int* in_sizes, int n_in,
                              void* d_out, int out_size, void* d_ws, size_t ws_size,
                              hipStream_t stream) {
    const float* x   = (const float*)d_in[0];
    const float* y   = (const float*)d_in[1];
    const float* c1w = (const float*)d_in[2];
    const float* c1b = (const float*)d_in[3];
    const float* pw  = (const float*)d_in[4];
    const float* pb  = (const float*)d_in[5];
    const float* dw  = (const float*)d_in[6];
    const float* db  = (const float*)d_in[7];
    const float* w1  = (const float*)d_in[8];
    const float* b1  = (const float*)d_in[9];
    const float* w2  = (const float*)d_in[10];
    const float* b2  = (const float*)d_in[11];
    const float* w3  = (const float*)d_in[12];
    const float* b3  = (const float*)d_in[13];
    float* out = (float*)d_out;
    char* ws = (char*)d_ws;

    static const int exp_sizes[14] = {200704, 2560, 20736, 256, 5308416, 256,
                                      1474560, 160, 81920, 512, 524288, 1024,
                                      802816, 784};
    int bad = (n_in == 14) ? -1 : -2;
    if (bad == -1)
        for (int i = 0; i < 14; ++i) if (in_sizes[i] != exp_sizes[i]) { bad = i; break; }
    if (bad != -1) {
        fill_sentinel<<<(out_size + 255) / 256, 256, 0, stream>>>(out, out_size,
            7168.f + 16.f * (float)(bad + 1));
        return;
    }
    const size_t NEEDED = 72482816ULL;
    if (ws_size < NEEDED) {
        fill_sentinel<<<(out_size + 255) / 256, 256, 0, stream>>>(out, out_size, 111.0f);
        return;
    }

    // layout: peak live = h + wT2 + x3m (72.5 MB)
    u16*   h       = (u16*)(ws);                    // [0, 52,428,800)
    u16*   wT2     = (u16*)(ws + 52428800);         // [52,428,800, 63,045,632)
    float* x3m     = (float*)(ws + 63045632);       // [63,045,632, 72,482,816)  preact->x3 in place
    // after GEMM, h/wT2 dead: overlay routing/recon scratch
    float* logits  = (float*)(ws);                  // 11,796,480
    float* act     = (float*)(ws + 11796480);       //    163,840
    float* masked  = (float*)(ws + 11960320);       //    163,840
    float* r1      = (float*)(ws + 12124160);       //    524,288
    float* r2      = (float*)(ws + 12648448);       //  1,048,576
    float* preactD = (float*)(ws + 13697024);       //    163,840

    conv1_kernel<<<1024, 256, 0, stream>>>(x, c1w, c1b, h);
    transpose_primw<<<256, 256, 0, stream>>>(pw, wT2);
    hipMemsetAsync(x3m, 0, 9437184, stream);
    prim_gemm_split<<<dim3(144, 8), 256, 0, stream>>>(h, wT2, x3m);
    squash_kernel<<<9216, 256, 0, stream>>>(x3m, pb);

    // routing iter 1 (uniform), 2, 3
    hipMemsetAsync(preactD, 0, 163840, stream);
    routing_act_part<<<dim3(9, 32), 256, 0, stream>>>(x3m, dw, logits, preactD, 1);
    routing_squash<<<256, 192, 0, stream>>>(preactD, db, act, (float*)nullptr);
    routing_upd_part<<<dim3(9, 32), 256, 0, stream>>>(x3m, dw, act, logits, 1);

    hipMemsetAsync(preactD, 0, 163840, stream);
    routing_act_part<<<dim3(9, 32), 256, 0, stream>>>(x3m, dw, logits, preactD, 0);
    routing_squash<<<256, 192, 0, stream>>>(preactD, db, act, (float*)nullptr);
    routing_upd_part<<<dim3(9, 32), 256, 0, stream>>>(x3m, dw, act, logits, 0);

    hipMemsetAsync(preactD, 0, 163840, stream);
    routing_act_part<<<dim3(9, 32), 256, 0, stream>>>(x3m, dw, logits, preactD, 0);
    routing_squash<<<256, 192, 0, stream>>>(preactD, db, act, out);

    // reconstruction
    masked_kernel<<<160, 256, 0, stream>>>(act, y, masked);
    mlp_layer<<<dim3(128, 2), 256, 0, stream>>>(masked, w1, b1, r1, 160, 512, 0);
    mlp_layer<<<dim3(128, 4), 256, 0, stream>>>(r1, w2, b2, r2, 512, 1024, 0);
    mlp_layer<<<dim3(128, 4), 256, 0, stream>>>(r2, w3, b3, out + 40960, 1024, 784, 1);
}